// Round 7
// baseline (215.663 us; speedup 1.0000x reference)
//
#include <hip/hip_runtime.h>
#include <math.h>

#define B_ 64
#define L_ 512
#define E_ 256
#define H_ 256
#define R_ 50
#define NEG_ 1.0e10f

typedef __bf16 bf16x8 __attribute__((ext_vector_type(8)));
typedef float f32x4 __attribute__((ext_vector_type(4)));

__device__ __forceinline__ float sigmoidf_(float x) { return 1.0f / (1.0f + expf(-x)); }
__device__ __forceinline__ float geluf_(float x) { return 0.5f * x * (1.0f + erff(x * 0.7071067811865476f)); }
__device__ __forceinline__ unsigned short f2bf(float x) {
    unsigned u = __float_as_uint(x);
    return (unsigned short)((u + 0x7fffu + ((u >> 16) & 1u)) >> 16);
}
__device__ __forceinline__ float bf2f(unsigned u) { return __uint_as_float(u << 16); }

// ---------------- fused one-time converts / packs (single launch) ----------------
__global__ void k_packs(const float* __restrict__ encoder_o, unsigned short* __restrict__ encBF0,
                        const float* __restrict__ conv_ent_w, const float* __restrict__ conv_rel_w,
                        unsigned short* __restrict__ bpE, unsigned short* __restrict__ bpR,
                        const float* __restrict__ W_rel, unsigned short* __restrict__ wpR,
                        float* __restrict__ wpkE, float* __restrict__ wpkR,
                        const float* __restrict__ W_attn, float* __restrict__ WTat) {
    const int blk = blockIdx.x, t = threadIdx.x;
    if (blk < 8192) {
        size_t idx = (size_t)blk * 256 + t;
        float4 v = *(const float4*)&encoder_o[idx * 4];
        uint2 p;
        p.x = (unsigned)f2bf(v.x) | ((unsigned)f2bf(v.y) << 16);
        p.y = (unsigned)f2bf(v.z) | ((unsigned)f2bf(v.w) << 16);
        *(uint2*)&encBF0[idx * 4] = p;
    } else if (blk < 8384) {
        const float* w = (blk < 8288) ? conv_ent_w : conv_rel_w;
        unsigned short* bp = (blk < 8288) ? bpE : bpR;
        int idx = (blk - ((blk < 8288) ? 8192 : 8288)) * 256 + t;
        int l = idx & 63, kc = (idx >> 6) % 24, of = idx / (24 * 64);
        int o = of * 16 + (l & 15);
        int k = kc >> 3;
        int cb = ((kc & 7) << 5) + ((l >> 4) << 3);
        unsigned short v[8];
#pragma unroll
        for (int j = 0; j < 8; ++j) v[j] = f2bf(w[(size_t)o * 1536 + (size_t)(cb + j) * 3 + k]);
        unsigned int* dst = (unsigned int*)&bp[(size_t)idx * 8];
#pragma unroll
        for (int j = 0; j < 4; ++j) dst[j] = (unsigned int)v[2 * j] | ((unsigned int)v[2 * j + 1] << 16);
    } else if (blk < 8392) {
        int idx = (blk - 8384) * 256 + t;
        int l = idx & 63, kc = (idx >> 6) & 7, of = idx / (8 * 64);
        int r = of * 16 + (l & 15);
        int k = kc * 32 + ((l >> 4) << 3);
        unsigned short v[8];
#pragma unroll
        for (int j = 0; j < 8; ++j) v[j] = (r < R_) ? f2bf(W_rel[(size_t)r * E_ + k + j]) : 0;
        unsigned int* dst = (unsigned int*)&wpR[(size_t)idx * 8];
#pragma unroll
        for (int j = 0; j < 4; ++j) dst[j] = (unsigned int)v[2 * j] | ((unsigned int)v[2 * j + 1] << 16);
    } else if (blk < 8904) {
        const float* w = (blk < 8648) ? conv_ent_w : conv_rel_w;
        float* wpk = (blk < 8648) ? wpkE : wpkR;
        int idx = (blk - ((blk < 8648) ? 8392 : 8648)) * 256 + t;
        int o = idx >> 8, c = idx & 255;
        const float* p = &w[(size_t)o * 1536 + 768 + c * 3];
        float w0 = p[0], w1 = p[1], w2 = p[2];
        wpk[c * 256 + o] = w0;
        wpk[65536 + c * 256 + o] = w0 + w1 + w2;
        wpk[131072 + c * 256 + o] = w2;
    } else {
        int idx = (blk - 8904) * 256 + t;
        int o = idx >> 9, k = idx & 511;
        WTat[k * 256 + o] = W_attn[idx];
    }
}

// ---------------- LSTM gemm, split-K: grid (16, 2, 2) ----------------
template <int MODE>
__global__ __launch_bounds__(256) void k_lstm_gemm(
    const float* __restrict__ xsrc_f, const unsigned short* __restrict__ encg,
    const int* __restrict__ i1, const int* __restrict__ i2, const int* __restrict__ rin,
    const float* __restrict__ hprev,
    const float* __restrict__ W_ih, const float* __restrict__ W_hh,
    float* __restrict__ gates) {
    const int g0 = blockIdx.x * 64;
    const int half = blockIdx.y, z = blockIdx.z;
    const int t = threadIdx.x, tx = t & 15, ty = t >> 4;
    __shared__ float Xs[64][68];
    __shared__ float Wt[64][68];
    const float* Wsrc = half ? W_hh : W_ih;
    float acc[4][4] = {{0.f}};
    for (int kb = z * 128; kb < z * 128 + 128; kb += 64) {
        __syncthreads();
#pragma unroll
        for (int i = 0; i < 4; ++i) {
            int idx = i * 256 + t;
            int row = idx >> 4, kk = (idx & 15) << 2;
            float4 xv;
            if (half) {
                xv = *(const float4*)&hprev[row * 256 + kb + kk];
            } else if (MODE == 0) {
                xv = *(const float4*)&xsrc_f[kb + kk];
            } else if (MODE == 2) {
                xv = *(const float4*)&xsrc_f[(size_t)rin[row] * 256 + kb + kk];
            } else {
                const unsigned short* p1 = &encg[((size_t)row * L_ + i1[row]) * E_ + kb + kk];
                const unsigned short* p2 = &encg[((size_t)row * L_ + i2[row]) * E_ + kb + kk];
                uint2 a = *(const uint2*)p1, b2 = *(const uint2*)p2;
                xv.x = bf2f(a.x & 0xffffu) + bf2f(b2.x & 0xffffu);
                xv.y = bf2f(a.x >> 16) + bf2f(b2.x >> 16);
                xv.z = bf2f(a.y & 0xffffu) + bf2f(b2.y & 0xffffu);
                xv.w = bf2f(a.y >> 16) + bf2f(b2.y >> 16);
            }
            *(float4*)&Xs[row][kk] = xv;
            *(float4*)&Wt[row][kk] = *(const float4*)&Wsrc[(size_t)(g0 + row) * 256 + kb + kk];
        }
        __syncthreads();
#pragma unroll
        for (int kk = 0; kk < 64; kk += 4) {
            float4 xv[4], wv[4];
#pragma unroll
            for (int i = 0; i < 4; ++i) xv[i] = *(const float4*)&Xs[ty * 4 + i][kk];
#pragma unroll
            for (int j = 0; j < 4; ++j) wv[j] = *(const float4*)&Wt[tx * 4 + j][kk];
#pragma unroll
            for (int i = 0; i < 4; ++i)
#pragma unroll
                for (int j = 0; j < 4; ++j)
                    acc[i][j] += xv[i].x * wv[j].x + xv[i].y * wv[j].y + xv[i].z * wv[j].z + xv[i].w * wv[j].w;
        }
    }
    const int seg = half * 2 + z;
#pragma unroll
    for (int i = 0; i < 4; ++i)
#pragma unroll
        for (int j = 0; j < 4; ++j)
            gates[(size_t)seg * 65536 + (size_t)(ty * 4 + i) * 1024 + g0 + tx * 4 + j] = acc[i][j];
}

// ---------------- attention partial (64-l chunks) with fused LSTM finish ----------------
__global__ __launch_bounds__(256) void k_attn_part(
    const float* __restrict__ gates, const float* __restrict__ b_ih, const float* __restrict__ b_hh,
    const float* __restrict__ c_in, float* __restrict__ c_out, float* __restrict__ h_out,
    const unsigned short* __restrict__ encbf,
    float* __restrict__ mixp, float* __restrict__ stats) {
    int b = blockIdx.y, ch = blockIdx.x, t = threadIdx.x;
    __shared__ float hs[E_];
    __shared__ float scp[64][4];
    __shared__ float sc[64];
    {
        size_t ba = (size_t)b * 1024;
        float g4[4];
#pragma unroll
        for (int g = 0; g < 4; ++g) {
            float acc = b_ih[g * 256 + t] + b_hh[g * 256 + t];
#pragma unroll
            for (int seg = 0; seg < 4; ++seg) acc += gates[(size_t)seg * 65536 + ba + g * 256 + t];
            g4[g] = acc;
        }
        float c = sigmoidf_(g4[1]) * c_in[b * H_ + t] + sigmoidf_(g4[0]) * tanhf(g4[2]);
        float hv = sigmoidf_(g4[3]) * tanhf(c);
        hs[t] = hv;
        if (ch == 0) { h_out[b * H_ + t] = hv; c_out[b * H_ + t] = c; }
    }
    __syncthreads();
    {
        int row = t >> 2, es = t & 3;
        const uint4* p = (const uint4*)&encbf[((size_t)b * L_ + ch * 64 + row) * E_ + es * 64];
        float acc = 0.f;
#pragma unroll
        for (int k = 0; k < 8; ++k) {
            uint4 q = p[k];
            int e0 = es * 64 + k * 8;
            acc += bf2f(q.x & 0xffffu) * hs[e0] + bf2f(q.x >> 16) * hs[e0 + 1]
                 + bf2f(q.y & 0xffffu) * hs[e0 + 2] + bf2f(q.y >> 16) * hs[e0 + 3]
                 + bf2f(q.z & 0xffffu) * hs[e0 + 4] + bf2f(q.z >> 16) * hs[e0 + 5]
                 + bf2f(q.w & 0xffffu) * hs[e0 + 6] + bf2f(q.w >> 16) * hs[e0 + 7];
        }
        scp[row][es] = acc;
    }
    __syncthreads();
    if (t < 64) {
        float v = scp[t][0] + scp[t][1] + scp[t][2] + scp[t][3];
        float m = v;
#pragma unroll
        for (int off = 32; off; off >>= 1) m = fmaxf(m, __shfl_xor(m, off));
        float ev = expf(v - m);
        float s = ev;
#pragma unroll
        for (int off = 32; off; off >>= 1) s += __shfl_xor(s, off);
        sc[t] = ev;
        if (t == 0) {
            stats[((size_t)b * 8 + ch) * 2] = m;
            stats[((size_t)b * 8 + ch) * 2 + 1] = s;
        }
    }
    __syncthreads();
    float acc = 0.f;
    const unsigned short* base = &encbf[((size_t)b * L_ + ch * 64) * E_ + t];
#pragma unroll 8
    for (int l = 0; l < 64; ++l) acc += sc[l] * bf2f((unsigned)base[(size_t)l * E_]);
    mixp[((size_t)b * 8 + ch) * E_ + t] = acc;
}

// ---------------- post1: combine + attn-out GEMV (split-K) ----------------
__global__ __launch_bounds__(256) void k_post1(
    const float* __restrict__ mixp, const float* __restrict__ stats,
    const float* __restrict__ h, const float* __restrict__ WT_attn,
    const float* __restrict__ b_attn, float* __restrict__ aout) {
    int b = blockIdx.x, oc = blockIdx.y, t = threadIdx.x;
    __shared__ float cat[512];
    __shared__ float red[16][16][4];
    {
        float M = -3.0e38f;
#pragma unroll
        for (int i = 0; i < 8; ++i) M = fmaxf(M, stats[(b * 8 + i) * 2]);
        float denom = 0.f, mixv = 0.f;
#pragma unroll
        for (int i = 0; i < 8; ++i) {
            float w = expf(stats[(b * 8 + i) * 2] - M);
            denom += stats[(b * 8 + i) * 2 + 1] * w;
            mixv += mixp[((size_t)b * 8 + i) * E_ + t] * w;
        }
        cat[t] = mixv / denom;
        cat[256 + t] = h[b * H_ + t];
    }
    __syncthreads();
    int ocol = t & 15, ks = t >> 4;
    int o4 = oc * 64 + ocol * 4;
    float a0 = 0.f, a1 = 0.f, a2 = 0.f, a3 = 0.f;
    const float* wp = &WT_attn[(size_t)(ks * 32) * 256 + o4];
#pragma unroll 8
    for (int k = 0; k < 32; ++k) {
        float4 w = *(const float4*)&wp[(size_t)k * 256];
        float cv = cat[ks * 32 + k];
        a0 += cv * w.x; a1 += cv * w.y; a2 += cv * w.z; a3 += cv * w.w;
    }
    red[ks][ocol][0] = a0; red[ks][ocol][1] = a1; red[ks][ocol][2] = a2; red[ks][ocol][3] = a3;
    __syncthreads();
    if (t < 64) {
        int oc2 = t >> 2, j = t & 3;
        float s = 0.f;
#pragma unroll
        for (int k2 = 0; k2 < 16; ++k2) s += red[k2][oc2][j];
        int o = oc * 64 + t;
        aout[b * E_ + o] = tanhf(s + b_attn[o]);
    }
}

// ---------------- post2: ocontrib (split-K over c) ----------------
__global__ __launch_bounds__(256) void k_post2(
    const float* __restrict__ aout, const float* __restrict__ wpk,
    float* __restrict__ cr0, float* __restrict__ fullv, float* __restrict__ cr2) {
    int b = blockIdx.x, m = blockIdx.y, t = threadIdx.x;
    __shared__ float os[256];
    __shared__ float red[4][64][4];
    os[t] = aout[b * E_ + t];
    __syncthreads();
    int ocol = t & 63, cs = t >> 6;
    int o4 = ocol * 4;
    const float* wp = &wpk[(size_t)m * 65536 + (size_t)(cs * 64) * 256 + o4];
    float a0 = 0.f, a1 = 0.f, a2 = 0.f, a3 = 0.f;
#pragma unroll 8
    for (int c = 0; c < 64; ++c) {
        float4 w = *(const float4*)&wp[(size_t)c * 256];
        float v = os[cs * 64 + c];
        a0 += v * w.x; a1 += v * w.y; a2 += v * w.z; a3 += v * w.w;
    }
    red[cs][ocol][0] = a0; red[cs][ocol][1] = a1; red[cs][ocol][2] = a2; red[cs][ocol][3] = a3;
    __syncthreads();
    int oc2 = t >> 2, j = t & 3;
    float s = red[0][oc2][j] + red[1][oc2][j] + red[2][oc2][j] + red[3][oc2][j];
    float* dst = (m == 0) ? cr0 : (m == 1) ? fullv : cr2;
    dst[b * E_ + t] = s;
}

// ---------------- conv MFMA: 128l x 256o tile, 8 waves (each 64l x 64o, 4x4 frags) ----------------
template <bool FUSE_HEADS, bool WRITE_OUT>
__global__ __launch_bounds__(512, 4) void k_conv_mfma(
    const unsigned short* __restrict__ encbf, const unsigned short* __restrict__ bp,
    const float* __restrict__ bias, const float* __restrict__ fullv,
    const float* __restrict__ cr0, const float* __restrict__ cr2,
    unsigned short* __restrict__ enc_out,
    const float* __restrict__ w_e1, const float* __restrict__ b_e1,
    const float* __restrict__ w_e2, const float* __restrict__ b_e2,
    float* __restrict__ o1, float* __restrict__ o2) {
    const int b = blockIdx.y, l0 = blockIdx.x * 128;
    const int t = threadIdx.x, lane = t & 63, wid = t >> 6;
    __shared__ unsigned short As[130 * 256];   // swizzled input; reused as output tile
    __shared__ float hsum[2][4][128];

    // stage A (bf16, XOR-swizzled, zero halo): rows 0..129 <-> l = l0-1+row
    for (int u = t; u < 130 * 32; u += 512) {
        int row = u >> 5, cu = u & 31;
        int l = l0 - 1 + row;
        uint4 v = {0u, 0u, 0u, 0u};
        if (l >= 0 && l < L_) v = *(const uint4*)&encbf[((size_t)b * L_ + l) * E_ + cu * 8];
        *(uint4*)&As[row * 256 + ((cu ^ (row & 7)) << 3)] = v;
    }
    __syncthreads();

    const int og = wid & 3, lg = wid >> 2;   // 4 o-groups x 2 l-groups
    f32x4 zero = {0.f, 0.f, 0.f, 0.f};
    f32x4 acc[4][4];
#pragma unroll
    for (int i = 0; i < 4; ++i)
#pragma unroll
        for (int j = 0; j < 4; ++j) acc[i][j] = zero;
    const int arow = lane & 15, agrp = lane >> 4;
    const int rbase = lg * 64 + arow;

#pragma unroll 2
    for (int kc = 0; kc < 24; ++kc) {
        const int k = kc >> 3;
        const int g = ((kc & 7) << 2) + agrp;
        bf16x8 a[4], bv[4];
#pragma unroll
        for (int mi = 0; mi < 4; ++mi) {
            int r = rbase + mi * 16 + k;
            a[mi] = *(const bf16x8*)&As[r * 256 + ((g ^ (r & 7)) << 3)];
        }
#pragma unroll
        for (int ni = 0; ni < 4; ++ni)
            bv[ni] = *(const bf16x8*)&bp[(((size_t)(og * 4 + ni) * 24 + kc) * 64 + lane) * 8];
#pragma unroll
        for (int mi = 0; mi < 4; ++mi)
#pragma unroll
            for (int ni = 0; ni < 4; ++ni)
                acc[mi][ni] = __builtin_amdgcn_mfma_f32_16x16x32_bf16(a[mi], bv[ni], acc[mi][ni], 0, 0, 0);
    }

    // per-lane epilogue constants (edge corrections loaded lazily)
    float biasv[4], we1v[4], we2v[4];
#pragma unroll
    for (int ni = 0; ni < 4; ++ni) {
        int o = (og * 4 + ni) * 16 + (lane & 15);
        biasv[ni] = bias[o] + fullv[b * E_ + o];
        if (FUSE_HEADS) { we1v[ni] = w_e1[o]; we2v[ni] = w_e2[o]; }
    }
    __syncthreads();   // done reading As; reuse as output tile

#pragma unroll
    for (int mi = 0; mi < 4; ++mi) {
#pragma unroll
        for (int r = 0; r < 4; ++r) {
            int lloc = lg * 64 + mi * 16 + agrp * 4 + r;
            int lrow = l0 + lloc;
            float p1 = 0.f, p2 = 0.f;
#pragma unroll
            for (int ni = 0; ni < 4; ++ni) {
                int o = (og * 4 + ni) * 16 + (lane & 15);
                float vv = acc[mi][ni][r] + biasv[ni];
                if (lrow == 0) vv -= cr0[b * E_ + o];
                if (lrow == L_ - 1) vv -= cr2[b * E_ + o];
                if (WRITE_OUT) As[lloc * 256 + o] = f2bf(vv);
                if (FUSE_HEADS) {
                    float gv = geluf_(vv);
                    p1 += gv * we1v[ni];
                    p2 += gv * we2v[ni];
                }
            }
            if (FUSE_HEADS) {
#pragma unroll
                for (int off = 1; off < 16; off <<= 1) {
                    p1 += __shfl_xor(p1, off);
                    p2 += __shfl_xor(p2, off);
                }
                if ((lane & 15) == 0) {
                    hsum[0][og][lloc] = p1;
                    hsum[1][og][lloc] = p2;
                }
            }
        }
    }
    __syncthreads();

    if (WRITE_OUT) {
        for (int u = t; u < 128 * 32; u += 512) {
            int row = u >> 5, cu = u & 31;
            *(uint4*)&enc_out[((size_t)b * L_ + l0 + row) * E_ + cu * 8] = *(const uint4*)&As[row * 256 + cu * 8];
        }
    }
    if (FUSE_HEADS && t < 256) {
        int hh = t >> 7, row = t & 127;
        float s = hsum[hh][0][row] + hsum[hh][1][row] + hsum[hh][2][row] + hsum[hh][3][row];
        float* dst = hh ? o2 : o1;
        const float* bb = hh ? b_e2 : b_e1;
        dst[(size_t)b * L_ + l0 + row] = s + bb[0];
    }
}

// ---------------- relation head: MFMA gelu(enc) @ W_rel^T, masked max ----------------
__global__ __launch_bounds__(256) void k_relmax_mfma(
    const unsigned short* __restrict__ encbf, const unsigned short* __restrict__ wp,
    const float* __restrict__ b_rel, const int* __restrict__ T,
    float* __restrict__ pmax) {
    const int b = blockIdx.y, l0 = blockIdx.x * 64;
    const int t = threadIdx.x, lane = t & 63, wid = t >> 6;
    __shared__ unsigned short As[64 * 256];
    __shared__ int Tm[64];
    __shared__ float pm[4][64];

    if (t < 64) Tm[t] = T[b * L_ + l0 + t];
    for (int u = t; u < 64 * 32; u += 256) {
        int row = u >> 5, cu = u & 31;
        uint4 q = *(const uint4*)&encbf[((size_t)b * L_ + l0 + row) * E_ + cu * 8];
        unsigned short s[8];
        unsigned qa[4] = {q.x, q.y, q.z, q.w};
#pragma unroll
        for (int j = 0; j < 4; ++j) {
            s[2 * j] = f2bf(geluf_(bf2f(qa[j] & 0xffffu)));
            s[2 * j + 1] = f2bf(geluf_(bf2f(qa[j] >> 16)));
        }
        uint4 p;
        p.x = (unsigned)s[0] | ((unsigned)s[1] << 16);
        p.y = (unsigned)s[2] | ((unsigned)s[3] << 16);
        p.z = (unsigned)s[4] | ((unsigned)s[5] << 16);
        p.w = (unsigned)s[6] | ((unsigned)s[7] << 16);
        *(uint4*)&As[row * 256 + ((cu ^ (row & 7)) << 3)] = p;
    }
    __syncthreads();

    f32x4 zero = {0.f, 0.f, 0.f, 0.f};
    f32x4 acc[4] = {zero, zero, zero, zero};
    const int arow = wid * 16 + (lane & 15);
    const int agrp = lane >> 4;
#pragma unroll 2
    for (int kc = 0; kc < 8; ++kc) {
        int g = (kc << 2) + agrp;
        bf16x8 a0 = *(const bf16x8*)&As[arow * 256 + ((g ^ (arow & 7)) << 3)];
#pragma unroll
        for (int ni = 0; ni < 4; ++ni) {
            bf16x8 bv = *(const bf16x8*)&wp[(((size_t)ni * 8 + kc) * 64 + lane) * 8];
            acc[ni] = __builtin_amdgcn_mfma_f32_16x16x32_bf16(a0, bv, acc[ni], 0, 0, 0);
        }
    }

    const int lloc_base = wid * 16 + ((lane >> 4) << 2);
#pragma unroll
    for (int ni = 0; ni < 4; ++ni) {
        int r = ni * 16 + (lane & 15);
        float brel = (r < R_) ? b_rel[r] : 0.f;
        float v = -3.0e38f;
#pragma unroll
        for (int rg = 0; rg < 4; ++rg) {
            float logit = acc[ni][rg] + brel;
            float pen = (Tm[lloc_base + rg] > 0) ? 0.f : NEG_;
            v = fmaxf(v, logit - pen);
        }
        v = fmaxf(v, __shfl_xor(v, 16));
        v = fmaxf(v, __shfl_xor(v, 32));
        if (lane < 16) pm[wid][ni * 16 + lane] = v;
    }
    __syncthreads();
    if (t < 64) {
        float m = fmaxf(fmaxf(pm[0][t], pm[1][t]), fmaxf(pm[2][t], pm[3][t]));
        pmax[((size_t)b * 8 + blockIdx.x) * 64 + t] = m;
    }
}

__global__ void k_relmax_red(const float* __restrict__ pmax, float* __restrict__ t2rel) {
    int b = blockIdx.x, r = threadIdx.x;
    if (r >= R_) return;
    float m = -3.0e38f;
    for (int ch = 0; ch < 8; ++ch) m = fmaxf(m, pmax[((size_t)b * 8 + ch) * 64 + r]);
    t2rel[b * R_ + r] = m;
}

// ---------------- driver ----------------
extern "C" void kernel_launch(void* const* d_in, const int* in_sizes, int n_in,
                              void* d_out, int out_size, void* d_ws, size_t ws_size,
                              hipStream_t stream) {
    const float* encoder_o = (const float*)d_in[0];
    const float* h0 = (const float*)d_in[1];
    const float* c0 = (const float*)d_in[2];
    const float* sos_emb = (const float*)d_in[3];
    const float* rel_emb = (const float*)d_in[4];
    const float* W_ih = (const float*)d_in[5];
    const float* W_hh = (const float*)d_in[6];
    const float* b_ih = (const float*)d_in[7];
    const float* b_hh = (const float*)d_in[8];
    const float* W_attn = (const float*)d_in[9];
    const float* b_attn = (const float*)d_in[10];
    const float* conv_rel_w = (const float*)d_in[11];
    const float* conv_rel_b = (const float*)d_in[12];
    const float* conv_ent_w = (const float*)d_in[13];
    const float* conv_ent_b = (const float*)d_in[14];
    const float* W_rel = (const float*)d_in[15];
    const float* b_rel = (const float*)d_in[16];
    const float* w_e1 = (const float*)d_in[17];
    const float* b_e1 = (const float*)d_in[18];
    const float* w_e2 = (const float*)d_in[19];
    const float* b_e2 = (const float*)d_in[20];
    const int* T = (const int*)d_in[21];
    const int* R_in = (const int*)d_in[22];
    const int* S_K1 = (const int*)d_in[23];
    const int* S_K2 = (const int*)d_in[24];

    float* out = (float*)d_out;
    float* t1e1 = out;
    float* t1e2 = out + 32768;
    float* t2rel = out + 65536;
    float* t3e1 = out + 68736;
    float* t3e2 = out + 101504;

    float* ws = (float*)d_ws;
    size_t off = 0;
    unsigned short* encBF0 = (unsigned short*)(ws + off); off += (size_t)B_ * L_ * E_ / 2;
    unsigned short* encA = (unsigned short*)(ws + off); off += (size_t)B_ * L_ * E_ / 2;
    unsigned short* encB = (unsigned short*)(ws + off); off += (size_t)B_ * L_ * E_ / 2;
    float* gates = ws + off; off += 4 * 65536;
    float* hbuf = ws + off; off += B_ * H_;
    float* cb1 = ws + off; off += B_ * H_;
    float* cb2 = ws + off; off += B_ * H_;
    float* cb3 = ws + off; off += B_ * H_;
    float* mixp = ws + off; off += (size_t)B_ * 8 * E_;
    float* stats = ws + off; off += B_ * 8 * 2;
    float* aoutb = ws + off; off += B_ * E_;
    float* fullv = ws + off; off += B_ * E_;
    float* cr0 = ws + off; off += B_ * E_;
    float* cr2 = ws + off; off += B_ * E_;
    float* pmax = ws + off; off += B_ * 8 * 64;
    float* wpkE = ws + off; off += 3 * 65536;
    float* wpkR = ws + off; off += 3 * 65536;
    float* WTat = ws + off; off += 131072;
    unsigned short* bpE = (unsigned short*)(ws + off); off += 16 * 24 * 64 * 8 / 2;
    unsigned short* bpR = (unsigned short*)(ws + off); off += 16 * 24 * 64 * 8 / 2;
    unsigned short* wpR = (unsigned short*)(ws + off); off += 4 * 8 * 64 * 8 / 2;

    dim3 convGrid(4, B_);
    dim3 attnGrid(8, B_);
    dim3 rmGrid(8, B_);
    dim3 lstmGrid(16, 2, 2);
    dim3 p1Grid(B_, 4);
    dim3 p2Grid(B_, 3);

    // one-time packs (single launch)
    k_packs<<<9416, 256, 0, stream>>>(encoder_o, encBF0, conv_ent_w, conv_rel_w,
                                      bpE, bpR, W_rel, wpR, wpkE, wpkR, W_attn, WTat);

    // ---- step 1 ----
    k_lstm_gemm<0><<<lstmGrid, 256, 0, stream>>>(sos_emb, nullptr, nullptr, nullptr, nullptr,
                                                 h0, W_ih, W_hh, gates);
    k_attn_part<<<attnGrid, 256, 0, stream>>>(gates, b_ih, b_hh, c0, cb1, hbuf, encBF0, mixp, stats);
    k_post1<<<p1Grid, 256, 0, stream>>>(mixp, stats, hbuf, WTat, b_attn, aoutb);
    k_post2<<<p2Grid, 256, 0, stream>>>(aoutb, wpkE, cr0, fullv, cr2);
    k_conv_mfma<true, true><<<convGrid, 512, 0, stream>>>(encBF0, bpE, conv_ent_b, fullv, cr0, cr2,
                                                          encA, w_e1, b_e1, w_e2, b_e2, t1e1, t1e2);

    // ---- step 2 ----
    k_lstm_gemm<1><<<lstmGrid, 256, 0, stream>>>(nullptr, encA, S_K1, S_K2, nullptr,
                                                 hbuf, W_ih, W_hh, gates);
    k_attn_part<<<attnGrid, 256, 0, stream>>>(gates, b_ih, b_hh, cb1, cb2, hbuf, encA, mixp, stats);
    k_post1<<<p1Grid, 256, 0, stream>>>(mixp, stats, hbuf, WTat, b_attn, aoutb);
    k_post2<<<p2Grid, 256, 0, stream>>>(aoutb, wpkR, cr0, fullv, cr2);
    k_conv_mfma<false, true><<<convGrid, 512, 0, stream>>>(encA, bpR, conv_rel_b, fullv, cr0, cr2,
                                                           encB, nullptr, nullptr, nullptr, nullptr,
                                                           nullptr, nullptr);
    k_relmax_mfma<<<rmGrid, 256, 0, stream>>>(encB, wpR, b_rel, T, pmax);
    k_relmax_red<<<B_, 64, 0, stream>>>(pmax, t2rel);

    // ---- step 3 ----
    k_lstm_gemm<2><<<lstmGrid, 256, 0, stream>>>(rel_emb, nullptr, nullptr, nullptr, R_in,
                                                 hbuf, W_ih, W_hh, gates);
    k_attn_part<<<attnGrid, 256, 0, stream>>>(gates, b_ih, b_hh, cb2, cb3, hbuf, encB, mixp, stats);
    k_post1<<<p1Grid, 256, 0, stream>>>(mixp, stats, hbuf, WTat, b_attn, aoutb);
    k_post2<<<p2Grid, 256, 0, stream>>>(aoutb, wpkE, cr0, fullv, cr2);
    k_conv_mfma<true, false><<<convGrid, 512, 0, stream>>>(encB, bpE, conv_ent_b, fullv, cr0, cr2,
                                                           nullptr, w_e1, b_e1, w_e2, b_e2, t3e1, t3e2);
}

// Round 8
// 189.819 us; speedup vs baseline: 1.1361x; 1.1361x over previous
//
#include <hip/hip_runtime.h>
#include <math.h>

#define B_ 64
#define L_ 512
#define E_ 256
#define H_ 256
#define R_ 50
#define NEG_ 1.0e10f

typedef __bf16 bf16x8 __attribute__((ext_vector_type(8)));
typedef float f32x4 __attribute__((ext_vector_type(4)));

__device__ __forceinline__ float sigmoidf_(float x) { return 1.0f / (1.0f + expf(-x)); }
__device__ __forceinline__ float geluf_(float x) { return 0.5f * x * (1.0f + erff(x * 0.7071067811865476f)); }
__device__ __forceinline__ unsigned short f2bf(float x) {
    unsigned u = __float_as_uint(x);
    return (unsigned short)((u + 0x7fffu + ((u >> 16) & 1u)) >> 16);
}
__device__ __forceinline__ float bf2f(unsigned u) { return __uint_as_float(u << 16); }

// ---------------- fused one-time converts / packs (single launch) ----------------
__global__ void k_packs(const float* __restrict__ encoder_o, unsigned short* __restrict__ encBF0,
                        const float* __restrict__ conv_ent_w, const float* __restrict__ conv_rel_w,
                        unsigned short* __restrict__ bpE, unsigned short* __restrict__ bpR,
                        const float* __restrict__ W_rel, unsigned short* __restrict__ wpR,
                        float* __restrict__ wpkE, float* __restrict__ wpkR,
                        const float* __restrict__ W_attn, float* __restrict__ WTat) {
    const int blk = blockIdx.x, t = threadIdx.x;
    if (blk < 8192) {
        size_t idx = (size_t)blk * 256 + t;
        float4 v = *(const float4*)&encoder_o[idx * 4];
        uint2 p;
        p.x = (unsigned)f2bf(v.x) | ((unsigned)f2bf(v.y) << 16);
        p.y = (unsigned)f2bf(v.z) | ((unsigned)f2bf(v.w) << 16);
        *(uint2*)&encBF0[idx * 4] = p;
    } else if (blk < 8384) {
        const float* w = (blk < 8288) ? conv_ent_w : conv_rel_w;
        unsigned short* bp = (blk < 8288) ? bpE : bpR;
        int idx = (blk - ((blk < 8288) ? 8192 : 8288)) * 256 + t;
        int l = idx & 63, kc = (idx >> 6) % 24, of = idx / (24 * 64);
        int o = of * 16 + (l & 15);
        int k = kc >> 3;
        int cb = ((kc & 7) << 5) + ((l >> 4) << 3);
        unsigned short v[8];
#pragma unroll
        for (int j = 0; j < 8; ++j) v[j] = f2bf(w[(size_t)o * 1536 + (size_t)(cb + j) * 3 + k]);
        unsigned int* dst = (unsigned int*)&bp[(size_t)idx * 8];
#pragma unroll
        for (int j = 0; j < 4; ++j) dst[j] = (unsigned int)v[2 * j] | ((unsigned int)v[2 * j + 1] << 16);
    } else if (blk < 8392) {
        int idx = (blk - 8384) * 256 + t;
        int l = idx & 63, kc = (idx >> 6) & 7, of = idx / (8 * 64);
        int r = of * 16 + (l & 15);
        int k = kc * 32 + ((l >> 4) << 3);
        unsigned short v[8];
#pragma unroll
        for (int j = 0; j < 8; ++j) v[j] = (r < R_) ? f2bf(W_rel[(size_t)r * E_ + k + j]) : 0;
        unsigned int* dst = (unsigned int*)&wpR[(size_t)idx * 8];
#pragma unroll
        for (int j = 0; j < 4; ++j) dst[j] = (unsigned int)v[2 * j] | ((unsigned int)v[2 * j + 1] << 16);
    } else if (blk < 8904) {
        const float* w = (blk < 8648) ? conv_ent_w : conv_rel_w;
        float* wpk = (blk < 8648) ? wpkE : wpkR;
        int idx = (blk - ((blk < 8648) ? 8392 : 8648)) * 256 + t;
        int o = idx >> 8, c = idx & 255;
        const float* p = &w[(size_t)o * 1536 + 768 + c * 3];
        float w0 = p[0], w1 = p[1], w2 = p[2];
        wpk[c * 256 + o] = w0;
        wpk[65536 + c * 256 + o] = w0 + w1 + w2;
        wpk[131072 + c * 256 + o] = w2;
    } else {
        int idx = (blk - 8904) * 256 + t;
        int o = idx >> 9, k = idx & 511;
        WTat[k * 256 + o] = W_attn[idx];
    }
}

// ---------------- LSTM gemm, split-K: grid (16, 2, 2); MODE 2 also reduces pmax -> t2rel ----------------
template <int MODE>
__global__ __launch_bounds__(256) void k_lstm_gemm(
    const float* __restrict__ xsrc_f, const unsigned short* __restrict__ encg,
    const int* __restrict__ i1, const int* __restrict__ i2, const int* __restrict__ rin,
    const float* __restrict__ hprev,
    const float* __restrict__ W_ih, const float* __restrict__ W_hh,
    float* __restrict__ gates,
    const float* __restrict__ pmax, float* __restrict__ t2rel) {
    const int g0 = blockIdx.x * 64;
    const int half = blockIdx.y, z = blockIdx.z;
    const int t = threadIdx.x, tx = t & 15, ty = t >> 4;
    __shared__ float Xs[64][68];
    __shared__ float Wt[64][68];
    const float* Wsrc = half ? W_hh : W_ih;
    float acc[4][4] = {{0.f}};
    for (int kb = z * 128; kb < z * 128 + 128; kb += 64) {
        __syncthreads();
#pragma unroll
        for (int i = 0; i < 4; ++i) {
            int idx = i * 256 + t;
            int row = idx >> 4, kk = (idx & 15) << 2;
            float4 xv;
            if (half) {
                xv = *(const float4*)&hprev[row * 256 + kb + kk];
            } else if (MODE == 0) {
                xv = *(const float4*)&xsrc_f[kb + kk];
            } else if (MODE == 2) {
                xv = *(const float4*)&xsrc_f[(size_t)rin[row] * 256 + kb + kk];
            } else {
                const unsigned short* p1 = &encg[((size_t)row * L_ + i1[row]) * E_ + kb + kk];
                const unsigned short* p2 = &encg[((size_t)row * L_ + i2[row]) * E_ + kb + kk];
                uint2 a = *(const uint2*)p1, b2 = *(const uint2*)p2;
                xv.x = bf2f(a.x & 0xffffu) + bf2f(b2.x & 0xffffu);
                xv.y = bf2f(a.x >> 16) + bf2f(b2.x >> 16);
                xv.z = bf2f(a.y & 0xffffu) + bf2f(b2.y & 0xffffu);
                xv.w = bf2f(a.y >> 16) + bf2f(b2.y >> 16);
            }
            *(float4*)&Xs[row][kk] = xv;
            *(float4*)&Wt[row][kk] = *(const float4*)&Wsrc[(size_t)(g0 + row) * 256 + kb + kk];
        }
        __syncthreads();
#pragma unroll
        for (int kk = 0; kk < 64; kk += 4) {
            float4 xv[4], wv[4];
#pragma unroll
            for (int i = 0; i < 4; ++i) xv[i] = *(const float4*)&Xs[ty * 4 + i][kk];
#pragma unroll
            for (int j = 0; j < 4; ++j) wv[j] = *(const float4*)&Wt[tx * 4 + j][kk];
#pragma unroll
            for (int i = 0; i < 4; ++i)
#pragma unroll
                for (int j = 0; j < 4; ++j)
                    acc[i][j] += xv[i].x * wv[j].x + xv[i].y * wv[j].y + xv[i].z * wv[j].z + xv[i].w * wv[j].w;
        }
    }
    const int seg = half * 2 + z;
#pragma unroll
    for (int i = 0; i < 4; ++i)
#pragma unroll
        for (int j = 0; j < 4; ++j)
            gates[(size_t)seg * 65536 + (size_t)(ty * 4 + i) * 1024 + g0 + tx * 4 + j] = acc[i][j];

    // MODE 2 runs after conv2: one block reduces pmax -> t2rel (kills k_relmax_red dispatch)
    if (MODE == 2 && blockIdx.x == 0 && half == 0 && z == 0) {
        for (int i = t; i < B_ * 64; i += 256) {
            int b = i >> 6, r = i & 63;
            if (r < R_) {
                float m = -3.0e38f;
#pragma unroll
                for (int ch = 0; ch < 8; ++ch) m = fmaxf(m, pmax[((size_t)b * 8 + ch) * 64 + r]);
                t2rel[b * R_ + r] = m;
            }
        }
    }
}

// ---------------- attention partial (64-l chunks) with fused LSTM finish ----------------
__global__ __launch_bounds__(256) void k_attn_part(
    const float* __restrict__ gates, const float* __restrict__ b_ih, const float* __restrict__ b_hh,
    const float* __restrict__ c_in, float* __restrict__ c_out, float* __restrict__ h_out,
    const unsigned short* __restrict__ encbf,
    float* __restrict__ mixp, float* __restrict__ stats) {
    int b = blockIdx.y, ch = blockIdx.x, t = threadIdx.x;
    __shared__ float hs[E_];
    __shared__ float scp[64][4];
    __shared__ float sc[64];
    {
        size_t ba = (size_t)b * 1024;
        float g4[4];
#pragma unroll
        for (int g = 0; g < 4; ++g) {
            float acc = b_ih[g * 256 + t] + b_hh[g * 256 + t];
#pragma unroll
            for (int seg = 0; seg < 4; ++seg) acc += gates[(size_t)seg * 65536 + ba + g * 256 + t];
            g4[g] = acc;
        }
        float c = sigmoidf_(g4[1]) * c_in[b * H_ + t] + sigmoidf_(g4[0]) * tanhf(g4[2]);
        float hv = sigmoidf_(g4[3]) * tanhf(c);
        hs[t] = hv;
        if (ch == 0) { h_out[b * H_ + t] = hv; c_out[b * H_ + t] = c; }
    }
    __syncthreads();
    {
        int row = t >> 2, es = t & 3;
        const uint4* p = (const uint4*)&encbf[((size_t)b * L_ + ch * 64 + row) * E_ + es * 64];
        float acc = 0.f;
#pragma unroll
        for (int k = 0; k < 8; ++k) {
            uint4 q = p[k];
            int e0 = es * 64 + k * 8;
            acc += bf2f(q.x & 0xffffu) * hs[e0] + bf2f(q.x >> 16) * hs[e0 + 1]
                 + bf2f(q.y & 0xffffu) * hs[e0 + 2] + bf2f(q.y >> 16) * hs[e0 + 3]
                 + bf2f(q.z & 0xffffu) * hs[e0 + 4] + bf2f(q.z >> 16) * hs[e0 + 5]
                 + bf2f(q.w & 0xffffu) * hs[e0 + 6] + bf2f(q.w >> 16) * hs[e0 + 7];
        }
        scp[row][es] = acc;
    }
    __syncthreads();
    if (t < 64) {
        float v = scp[t][0] + scp[t][1] + scp[t][2] + scp[t][3];
        float m = v;
#pragma unroll
        for (int off = 32; off; off >>= 1) m = fmaxf(m, __shfl_xor(m, off));
        float ev = expf(v - m);
        float s = ev;
#pragma unroll
        for (int off = 32; off; off >>= 1) s += __shfl_xor(s, off);
        sc[t] = ev;
        if (t == 0) {
            stats[((size_t)b * 8 + ch) * 2] = m;
            stats[((size_t)b * 8 + ch) * 2 + 1] = s;
        }
    }
    __syncthreads();
    float acc = 0.f;
    const unsigned short* base = &encbf[((size_t)b * L_ + ch * 64) * E_ + t];
#pragma unroll 8
    for (int l = 0; l < 64; ++l) acc += sc[l] * bf2f((unsigned)base[(size_t)l * E_]);
    mixp[((size_t)b * 8 + ch) * E_ + t] = acc;
}

// ---------------- post1: combine + attn-out GEMV (split-K) ----------------
__global__ __launch_bounds__(256) void k_post1(
    const float* __restrict__ mixp, const float* __restrict__ stats,
    const float* __restrict__ h, const float* __restrict__ WT_attn,
    const float* __restrict__ b_attn, float* __restrict__ aout) {
    int b = blockIdx.x, oc = blockIdx.y, t = threadIdx.x;
    __shared__ float cat[512];
    __shared__ float red[16][16][4];
    {
        float M = -3.0e38f;
#pragma unroll
        for (int i = 0; i < 8; ++i) M = fmaxf(M, stats[(b * 8 + i) * 2]);
        float denom = 0.f, mixv = 0.f;
#pragma unroll
        for (int i = 0; i < 8; ++i) {
            float w = expf(stats[(b * 8 + i) * 2] - M);
            denom += stats[(b * 8 + i) * 2 + 1] * w;
            mixv += mixp[((size_t)b * 8 + i) * E_ + t] * w;
        }
        cat[t] = mixv / denom;
        cat[256 + t] = h[b * H_ + t];
    }
    __syncthreads();
    int ocol = t & 15, ks = t >> 4;
    int o4 = oc * 64 + ocol * 4;
    float a0 = 0.f, a1 = 0.f, a2 = 0.f, a3 = 0.f;
    const float* wp = &WT_attn[(size_t)(ks * 32) * 256 + o4];
#pragma unroll 8
    for (int k = 0; k < 32; ++k) {
        float4 w = *(const float4*)&wp[(size_t)k * 256];
        float cv = cat[ks * 32 + k];
        a0 += cv * w.x; a1 += cv * w.y; a2 += cv * w.z; a3 += cv * w.w;
    }
    red[ks][ocol][0] = a0; red[ks][ocol][1] = a1; red[ks][ocol][2] = a2; red[ks][ocol][3] = a3;
    __syncthreads();
    if (t < 64) {
        int oc2 = t >> 2, j = t & 3;
        float s = 0.f;
#pragma unroll
        for (int k2 = 0; k2 < 16; ++k2) s += red[k2][oc2][j];
        int o = oc * 64 + t;
        aout[b * E_ + o] = tanhf(s + b_attn[o]);
    }
}

// ---------------- post2: ocontrib (split-K over c) ----------------
__global__ __launch_bounds__(256) void k_post2(
    const float* __restrict__ aout, const float* __restrict__ wpk,
    float* __restrict__ cr0, float* __restrict__ fullv, float* __restrict__ cr2) {
    int b = blockIdx.x, m = blockIdx.y, t = threadIdx.x;
    __shared__ float os[256];
    __shared__ float red[4][64][4];
    os[t] = aout[b * E_ + t];
    __syncthreads();
    int ocol = t & 63, cs = t >> 6;
    int o4 = ocol * 4;
    const float* wp = &wpk[(size_t)m * 65536 + (size_t)(cs * 64) * 256 + o4];
    float a0 = 0.f, a1 = 0.f, a2 = 0.f, a3 = 0.f;
#pragma unroll 8
    for (int c = 0; c < 64; ++c) {
        float4 w = *(const float4*)&wp[(size_t)c * 256];
        float v = os[cs * 64 + c];
        a0 += v * w.x; a1 += v * w.y; a2 += v * w.z; a3 += v * w.w;
    }
    red[cs][ocol][0] = a0; red[cs][ocol][1] = a1; red[cs][ocol][2] = a2; red[cs][ocol][3] = a3;
    __syncthreads();
    int oc2 = t >> 2, j = t & 3;
    float s = red[0][oc2][j] + red[1][oc2][j] + red[2][oc2][j] + red[3][oc2][j];
    float* dst = (m == 0) ? cr0 : (m == 1) ? fullv : cr2;
    dst[b * E_ + t] = s;
}

// ---------------- conv MFMA: 64l x 256o, 8 waves (2 o-frags each), A+B prefetch ----------------
// optional fused: entity heads; relation masked-max head (rel GEMM from in-place gelu'd tile)
template <bool FUSE_HEADS, bool WRITE_OUT, bool FUSE_REL>
__global__ __launch_bounds__(512, 4) void k_conv_mfma(
    const unsigned short* __restrict__ encbf, const unsigned short* __restrict__ bp,
    const float* __restrict__ bias, const float* __restrict__ fullv,
    const float* __restrict__ cr0, const float* __restrict__ cr2,
    unsigned short* __restrict__ enc_out,
    const float* __restrict__ w_e1, const float* __restrict__ b_e1,
    const float* __restrict__ w_e2, const float* __restrict__ b_e2,
    float* __restrict__ o1, float* __restrict__ o2,
    const unsigned short* __restrict__ wprel, const float* __restrict__ b_rel,
    const int* __restrict__ T, float* __restrict__ pmax) {
    const int b = blockIdx.y, l0 = blockIdx.x * 64;
    const int t = threadIdx.x, lane = t & 63, wid = t >> 6;
    __shared__ unsigned short As[66 * 256];
    __shared__ float hsum[2][FUSE_HEADS ? 8 : 1][FUSE_HEADS ? 64 : 1];
    __shared__ float pm[FUSE_REL ? 8 : 1][2][16];
    __shared__ int Tm[FUSE_REL ? 64 : 1];

    if (FUSE_REL && t < 64) Tm[t] = T[b * L_ + l0 + t];

    // stage A (bf16 copy, XOR-swizzled, zero halo)
    for (int u = t; u < 66 * 32; u += 512) {
        int row = u >> 5, cu = u & 31;
        int l = l0 - 1 + row;
        uint4 v = {0u, 0u, 0u, 0u};
        if (l >= 0 && l < L_) v = *(const uint4*)&encbf[((size_t)b * L_ + l) * E_ + cu * 8];
        *(uint4*)&As[row * 256 + ((cu ^ (row & 7)) << 3)] = v;
    }
    __syncthreads();

    const int wo2 = wid * 2;                 // this wave's 2 o-frags (32 o)
    f32x4 zero = {0.f, 0.f, 0.f, 0.f};
    f32x4 acc[4][2];
#pragma unroll
    for (int i = 0; i < 4; ++i) { acc[i][0] = zero; acc[i][1] = zero; }
    const int arow = lane & 15, agrp = lane >> 4;
    const unsigned short* bp0 = &bp[((size_t)wo2 * 24 * 64 + lane) * 8];
    const unsigned short* bp1 = &bp[((size_t)(wo2 + 1) * 24 * 64 + lane) * 8];

    bf16x8 bc0 = *(const bf16x8*)bp0;
    bf16x8 bc1 = *(const bf16x8*)bp1;
    bf16x8 a[4];
#pragma unroll
    for (int mi = 0; mi < 4; ++mi) {
        int r = mi * 16 + arow;              // kc=0: k=0, g=agrp
        a[mi] = *(const bf16x8*)&As[r * 256 + ((agrp ^ (r & 7)) << 3)];
    }
#pragma unroll 4
    for (int kc = 0; kc < 24; ++kc) {
        bf16x8 bn0, bn1, an[4];
        if (kc < 23) {
            bn0 = *(const bf16x8*)&bp0[(size_t)(kc + 1) * 512];
            bn1 = *(const bf16x8*)&bp1[(size_t)(kc + 1) * 512];
            const int kn = (kc + 1) >> 3;
            const int gn = (((kc + 1) & 7) << 2) + agrp;
#pragma unroll
            for (int mi = 0; mi < 4; ++mi) {
                int r = mi * 16 + arow + kn;
                an[mi] = *(const bf16x8*)&As[r * 256 + ((gn ^ (r & 7)) << 3)];
            }
        }
#pragma unroll
        for (int mi = 0; mi < 4; ++mi) {
            acc[mi][0] = __builtin_amdgcn_mfma_f32_16x16x32_bf16(a[mi], bc0, acc[mi][0], 0, 0, 0);
            acc[mi][1] = __builtin_amdgcn_mfma_f32_16x16x32_bf16(a[mi], bc1, acc[mi][1], 0, 0, 0);
        }
        if (kc < 23) {
            bc0 = bn0; bc1 = bn1;
            a[0] = an[0]; a[1] = an[1]; a[2] = an[2]; a[3] = an[3];
        }
    }

    float biasv[2], c0v[2], c2v[2], we1v[2], we2v[2];
#pragma unroll
    for (int ni = 0; ni < 2; ++ni) {
        int o = (wo2 + ni) * 16 + (lane & 15);
        biasv[ni] = bias[o] + fullv[b * E_ + o];
        c0v[ni] = cr0[b * E_ + o];
        c2v[ni] = cr2[b * E_ + o];
        if (FUSE_HEADS) { we1v[ni] = w_e1[o]; we2v[ni] = w_e2[o]; }
    }
    __syncthreads();   // done reading As; reuse as output tile

#pragma unroll
    for (int mi = 0; mi < 4; ++mi) {
#pragma unroll
        for (int r = 0; r < 4; ++r) {
            int lloc = mi * 16 + agrp * 4 + r;
            int lrow = l0 + lloc;
            float p1 = 0.f, p2 = 0.f;
#pragma unroll
            for (int ni = 0; ni < 2; ++ni) {
                int o = (wo2 + ni) * 16 + (lane & 15);
                float vv = acc[mi][ni][r] + biasv[ni];
                if (lrow == 0) vv -= c0v[ni];
                if (lrow == L_ - 1) vv -= c2v[ni];
                if (WRITE_OUT || FUSE_REL) {
                    int idx = FUSE_REL ? (lloc * 256 + ((((o >> 3) ^ (lloc & 7))) << 3) + (o & 7))
                                       : (lloc * 256 + o);
                    As[idx] = f2bf(vv);
                }
                if (FUSE_HEADS) {
                    float gv = geluf_(vv);
                    p1 += gv * we1v[ni];
                    p2 += gv * we2v[ni];
                }
            }
            if (FUSE_HEADS) {
#pragma unroll
                for (int off = 1; off < 16; off <<= 1) {
                    p1 += __shfl_xor(p1, off);
                    p2 += __shfl_xor(p2, off);
                }
                if ((lane & 15) == 0) {
                    hsum[0][wid][lloc] = p1;
                    hsum[1][wid][lloc] = p2;
                }
            }
        }
    }
    __syncthreads();

    if (WRITE_OUT) {
        for (int u = t; u < 64 * 32; u += 512) {
            int row = u >> 5, cu = u & 31;
            int src = FUSE_REL ? (row * 256 + ((cu ^ (row & 7)) << 3)) : (row * 256 + cu * 8);
            uint4 q = *(const uint4*)&As[src];
            *(uint4*)&enc_out[((size_t)b * L_ + l0 + row) * E_ + cu * 8] = q;
            if (FUSE_REL) {
                // in-place gelu rewrite for the rel GEMM A-operand
                unsigned qa[4] = {q.x, q.y, q.z, q.w};
#pragma unroll
                for (int j = 0; j < 4; ++j) {
                    unsigned lo = f2bf(geluf_(bf2f(qa[j] & 0xffffu)));
                    unsigned hi = f2bf(geluf_(bf2f(qa[j] >> 16)));
                    qa[j] = lo | (hi << 16);
                }
                uint4 gq = {qa[0], qa[1], qa[2], qa[3]};
                *(uint4*)&As[src] = gq;
            }
        }
    }
    if (FUSE_HEADS && t < 128) {
        int hh = t >> 6, row = t & 63;
        float s = 0.f;
#pragma unroll
        for (int w = 0; w < 8; ++w) s += hsum[hh][w][row];
        float* dst = hh ? o2 : o1;
        const float* bb = hh ? b_e2 : b_e1;
        dst[(size_t)b * L_ + l0 + row] = s + bb[0];
    }
    if (FUSE_REL) {
        __syncthreads();
        // rel GEMM: 64l x 64r over K=256(o). wave -> (mi = wid&3 over l, njp = wid>>2 over r-pairs)
        const int mi = wid & 3, njp = wid >> 2;
        f32x4 accr[2] = {zero, zero};
        const int ar = mi * 16 + arow;
#pragma unroll 2
        for (int kc = 0; kc < 8; ++kc) {
            int g = (kc << 2) + agrp;
            bf16x8 av = *(const bf16x8*)&As[ar * 256 + ((g ^ (ar & 7)) << 3)];
#pragma unroll
            for (int q = 0; q < 2; ++q) {
                int nj = njp * 2 + q;
                bf16x8 bv = *(const bf16x8*)&wprel[(((size_t)nj * 8 + kc) * 64 + lane) * 8];
                accr[q] = __builtin_amdgcn_mfma_f32_16x16x32_bf16(av, bv, accr[q], 0, 0, 0);
            }
        }
#pragma unroll
        for (int q = 0; q < 2; ++q) {
            int nj = njp * 2 + q;
            int rr = nj * 16 + (lane & 15);
            float brel = (rr < R_) ? b_rel[rr] : 0.f;
            float v = -3.0e38f;
#pragma unroll
            for (int rg = 0; rg < 4; ++rg) {
                int lloc = mi * 16 + agrp * 4 + rg;
                float pen = (Tm[lloc] > 0) ? 0.f : NEG_;
                v = fmaxf(v, accr[q][rg] + brel - pen);
            }
            v = fmaxf(v, __shfl_xor(v, 16));
            v = fmaxf(v, __shfl_xor(v, 32));
            if (lane < 16) pm[wid][q][lane] = v;
        }
        __syncthreads();
        if (t < 64) {
            int nj = t >> 4, rl = t & 15;
            int q = nj & 1, wb = (nj >> 1) * 4;
            float m = fmaxf(fmaxf(pm[wb][q][rl], pm[wb + 1][q][rl]),
                            fmaxf(pm[wb + 2][q][rl], pm[wb + 3][q][rl]));
            pmax[((size_t)b * 8 + blockIdx.x) * 64 + t] = m;
        }
    }
}

// ---------------- driver ----------------
extern "C" void kernel_launch(void* const* d_in, const int* in_sizes, int n_in,
                              void* d_out, int out_size, void* d_ws, size_t ws_size,
                              hipStream_t stream) {
    const float* encoder_o = (const float*)d_in[0];
    const float* h0 = (const float*)d_in[1];
    const float* c0 = (const float*)d_in[2];
    const float* sos_emb = (const float*)d_in[3];
    const float* rel_emb = (const float*)d_in[4];
    const float* W_ih = (const float*)d_in[5];
    const float* W_hh = (const float*)d_in[6];
    const float* b_ih = (const float*)d_in[7];
    const float* b_hh = (const float*)d_in[8];
    const float* W_attn = (const float*)d_in[9];
    const float* b_attn = (const float*)d_in[10];
    const float* conv_rel_w = (const float*)d_in[11];
    const float* conv_rel_b = (const float*)d_in[12];
    const float* conv_ent_w = (const float*)d_in[13];
    const float* conv_ent_b = (const float*)d_in[14];
    const float* W_rel = (const float*)d_in[15];
    const float* b_rel = (const float*)d_in[16];
    const float* w_e1 = (const float*)d_in[17];
    const float* b_e1 = (const float*)d_in[18];
    const float* w_e2 = (const float*)d_in[19];
    const float* b_e2 = (const float*)d_in[20];
    const int* T = (const int*)d_in[21];
    const int* R_in = (const int*)d_in[22];
    const int* S_K1 = (const int*)d_in[23];
    const int* S_K2 = (const int*)d_in[24];

    float* out = (float*)d_out;
    float* t1e1 = out;
    float* t1e2 = out + 32768;
    float* t2rel = out + 65536;
    float* t3e1 = out + 68736;
    float* t3e2 = out + 101504;

    float* ws = (float*)d_ws;
    size_t off = 0;
    unsigned short* encBF0 = (unsigned short*)(ws + off); off += (size_t)B_ * L_ * E_ / 2;
    unsigned short* encA = (unsigned short*)(ws + off); off += (size_t)B_ * L_ * E_ / 2;
    unsigned short* encB = (unsigned short*)(ws + off); off += (size_t)B_ * L_ * E_ / 2;
    float* gates = ws + off; off += 4 * 65536;
    float* hbuf = ws + off; off += B_ * H_;
    float* cb1 = ws + off; off += B_ * H_;
    float* cb2 = ws + off; off += B_ * H_;
    float* cb3 = ws + off; off += B_ * H_;
    float* mixp = ws + off; off += (size_t)B_ * 8 * E_;
    float* stats = ws + off; off += B_ * 8 * 2;
    float* aoutb = ws + off; off += B_ * E_;
    float* fullv = ws + off; off += B_ * E_;
    float* cr0 = ws + off; off += B_ * E_;
    float* cr2 = ws + off; off += B_ * E_;
    float* pmax = ws + off; off += B_ * 8 * 64;
    float* wpkE = ws + off; off += 3 * 65536;
    float* wpkR = ws + off; off += 3 * 65536;
    float* WTat = ws + off; off += 131072;
    unsigned short* bpE = (unsigned short*)(ws + off); off += 16 * 24 * 64 * 8 / 2;
    unsigned short* bpR = (unsigned short*)(ws + off); off += 16 * 24 * 64 * 8 / 2;
    unsigned short* wpR = (unsigned short*)(ws + off); off += 4 * 8 * 64 * 8 / 2;

    dim3 convGrid(8, B_);
    dim3 attnGrid(8, B_);
    dim3 lstmGrid(16, 2, 2);
    dim3 p1Grid(B_, 4);
    dim3 p2Grid(B_, 3);

    // one-time packs (single launch)
    k_packs<<<9416, 256, 0, stream>>>(encoder_o, encBF0, conv_ent_w, conv_rel_w,
                                      bpE, bpR, W_rel, wpR, wpkE, wpkR, W_attn, WTat);

    // ---- step 1 ----
    k_lstm_gemm<0><<<lstmGrid, 256, 0, stream>>>(sos_emb, nullptr, nullptr, nullptr, nullptr,
                                                 h0, W_ih, W_hh, gates, nullptr, nullptr);
    k_attn_part<<<attnGrid, 256, 0, stream>>>(gates, b_ih, b_hh, c0, cb1, hbuf, encBF0, mixp, stats);
    k_post1<<<p1Grid, 256, 0, stream>>>(mixp, stats, hbuf, WTat, b_attn, aoutb);
    k_post2<<<p2Grid, 256, 0, stream>>>(aoutb, wpkE, cr0, fullv, cr2);
    k_conv_mfma<true, true, false><<<convGrid, 512, 0, stream>>>(
        encBF0, bpE, conv_ent_b, fullv, cr0, cr2, encA,
        w_e1, b_e1, w_e2, b_e2, t1e1, t1e2, nullptr, nullptr, nullptr, nullptr);

    // ---- step 2 ----
    k_lstm_gemm<1><<<lstmGrid, 256, 0, stream>>>(nullptr, encA, S_K1, S_K2, nullptr,
                                                 hbuf, W_ih, W_hh, gates, nullptr, nullptr);
    k_attn_part<<<attnGrid, 256, 0, stream>>>(gates, b_ih, b_hh, cb1, cb2, hbuf, encA, mixp, stats);
    k_post1<<<p1Grid, 256, 0, stream>>>(mixp, stats, hbuf, WTat, b_attn, aoutb);
    k_post2<<<p2Grid, 256, 0, stream>>>(aoutb, wpkR, cr0, fullv, cr2);
    k_conv_mfma<false, true, true><<<convGrid, 512, 0, stream>>>(
        encA, bpR, conv_rel_b, fullv, cr0, cr2, encB,
        nullptr, nullptr, nullptr, nullptr, nullptr, nullptr, wpR, b_rel, T, pmax);

    // ---- step 3 (lstm3 also reduces pmax -> t2rel) ----
    k_lstm_gemm<2><<<lstmGrid, 256, 0, stream>>>(rel_emb, nullptr, nullptr, nullptr, R_in,
                                                 hbuf, W_ih, W_hh, gates, pmax, t2rel);
    k_attn_part<<<attnGrid, 256, 0, stream>>>(gates, b_ih, b_hh, cb2, cb3, hbuf, encB, mixp, stats);
    k_post1<<<p1Grid, 256, 0, stream>>>(mixp, stats, hbuf, WTat, b_attn, aoutb);
    k_post2<<<p2Grid, 256, 0, stream>>>(aoutb, wpkE, cr0, fullv, cr2);
    k_conv_mfma<true, false, false><<<convGrid, 512, 0, stream>>>(
        encB, bpE, conv_ent_b, fullv, cr0, cr2, nullptr,
        w_e1, b_e1, w_e2, b_e2, t3e1, t3e2, nullptr, nullptr, nullptr, nullptr);
}

// Round 9
// 189.259 us; speedup vs baseline: 1.1395x; 1.0030x over previous
//
#include <hip/hip_runtime.h>
#include <math.h>

#define B_ 64
#define L_ 512
#define E_ 256
#define H_ 256
#define R_ 50
#define NEG_ 1.0e10f

typedef __bf16 bf16x8 __attribute__((ext_vector_type(8)));
typedef float f32x4 __attribute__((ext_vector_type(4)));

__device__ __forceinline__ float sigmoidf_(float x) { return 1.0f / (1.0f + expf(-x)); }
__device__ __forceinline__ float geluf_(float x) { return 0.5f * x * (1.0f + erff(x * 0.7071067811865476f)); }
__device__ __forceinline__ unsigned short f2bf(float x) {
    unsigned u = __float_as_uint(x);
    return (unsigned short)((u + 0x7fffu + ((u >> 16) & 1u)) >> 16);
}
__device__ __forceinline__ float bf2f(unsigned u) { return __uint_as_float(u << 16); }

// ---------------- fused one-time converts / packs (single launch) ----------------
__global__ void k_packs(const float* __restrict__ encoder_o, unsigned short* __restrict__ encBF0,
                        const float* __restrict__ conv_ent_w, const float* __restrict__ conv_rel_w,
                        unsigned short* __restrict__ bpE, unsigned short* __restrict__ bpR,
                        const float* __restrict__ W_rel, unsigned short* __restrict__ wpR,
                        float* __restrict__ wpkE, float* __restrict__ wpkR,
                        const float* __restrict__ W_attn, float* __restrict__ WTat) {
    const int blk = blockIdx.x, t = threadIdx.x;
    if (blk < 8192) {
        size_t idx = (size_t)blk * 256 + t;
        float4 v = *(const float4*)&encoder_o[idx * 4];
        uint2 p;
        p.x = (unsigned)f2bf(v.x) | ((unsigned)f2bf(v.y) << 16);
        p.y = (unsigned)f2bf(v.z) | ((unsigned)f2bf(v.w) << 16);
        *(uint2*)&encBF0[idx * 4] = p;
    } else if (blk < 8384) {
        const float* w = (blk < 8288) ? conv_ent_w : conv_rel_w;
        unsigned short* bp = (blk < 8288) ? bpE : bpR;
        int idx = (blk - ((blk < 8288) ? 8192 : 8288)) * 256 + t;
        int l = idx & 63, kc = (idx >> 6) % 24, of = idx / (24 * 64);
        int o = of * 16 + (l & 15);
        int k = kc >> 3;
        int cb = ((kc & 7) << 5) + ((l >> 4) << 3);
        unsigned short v[8];
#pragma unroll
        for (int j = 0; j < 8; ++j) v[j] = f2bf(w[(size_t)o * 1536 + (size_t)(cb + j) * 3 + k]);
        unsigned int* dst = (unsigned int*)&bp[(size_t)idx * 8];
#pragma unroll
        for (int j = 0; j < 4; ++j) dst[j] = (unsigned int)v[2 * j] | ((unsigned int)v[2 * j + 1] << 16);
    } else if (blk < 8392) {
        int idx = (blk - 8384) * 256 + t;
        int l = idx & 63, kc = (idx >> 6) & 7, of = idx / (8 * 64);
        int r = of * 16 + (l & 15);
        int k = kc * 32 + ((l >> 4) << 3);
        unsigned short v[8];
#pragma unroll
        for (int j = 0; j < 8; ++j) v[j] = (r < R_) ? f2bf(W_rel[(size_t)r * E_ + k + j]) : 0;
        unsigned int* dst = (unsigned int*)&wpR[(size_t)idx * 8];
#pragma unroll
        for (int j = 0; j < 4; ++j) dst[j] = (unsigned int)v[2 * j] | ((unsigned int)v[2 * j + 1] << 16);
    } else if (blk < 8904) {
        const float* w = (blk < 8648) ? conv_ent_w : conv_rel_w;
        float* wpk = (blk < 8648) ? wpkE : wpkR;
        int idx = (blk - ((blk < 8648) ? 8392 : 8648)) * 256 + t;
        int o = idx >> 8, c = idx & 255;
        const float* p = &w[(size_t)o * 1536 + 768 + c * 3];
        float w0 = p[0], w1 = p[1], w2 = p[2];
        wpk[c * 256 + o] = w0;
        wpk[65536 + c * 256 + o] = w0 + w1 + w2;
        wpk[131072 + c * 256 + o] = w2;
    } else {
        int idx = (blk - 8904) * 256 + t;
        int o = idx >> 9, k = idx & 511;
        WTat[k * 256 + o] = W_attn[idx];
    }
}

// ---------------- LSTM gemm, split-K: grid (16, 2, 2); MODE 2 also reduces pmax -> t2rel ----------------
template <int MODE>
__global__ __launch_bounds__(256) void k_lstm_gemm(
    const float* __restrict__ xsrc_f, const unsigned short* __restrict__ encg,
    const int* __restrict__ i1, const int* __restrict__ i2, const int* __restrict__ rin,
    const float* __restrict__ hprev,
    const float* __restrict__ W_ih, const float* __restrict__ W_hh,
    float* __restrict__ gates,
    const float* __restrict__ pmax, float* __restrict__ t2rel) {
    const int g0 = blockIdx.x * 64;
    const int half = blockIdx.y, z = blockIdx.z;
    const int t = threadIdx.x, tx = t & 15, ty = t >> 4;
    __shared__ float Xs[64][68];
    __shared__ float Wt[64][68];
    const float* Wsrc = half ? W_hh : W_ih;
    float acc[4][4] = {{0.f}};
    for (int kb = z * 128; kb < z * 128 + 128; kb += 64) {
        __syncthreads();
#pragma unroll
        for (int i = 0; i < 4; ++i) {
            int idx = i * 256 + t;
            int row = idx >> 4, kk = (idx & 15) << 2;
            float4 xv;
            if (half) {
                xv = *(const float4*)&hprev[row * 256 + kb + kk];
            } else if (MODE == 0) {
                xv = *(const float4*)&xsrc_f[kb + kk];
            } else if (MODE == 2) {
                xv = *(const float4*)&xsrc_f[(size_t)rin[row] * 256 + kb + kk];
            } else {
                const unsigned short* p1 = &encg[((size_t)row * L_ + i1[row]) * E_ + kb + kk];
                const unsigned short* p2 = &encg[((size_t)row * L_ + i2[row]) * E_ + kb + kk];
                uint2 a = *(const uint2*)p1, b2 = *(const uint2*)p2;
                xv.x = bf2f(a.x & 0xffffu) + bf2f(b2.x & 0xffffu);
                xv.y = bf2f(a.x >> 16) + bf2f(b2.x >> 16);
                xv.z = bf2f(a.y & 0xffffu) + bf2f(b2.y & 0xffffu);
                xv.w = bf2f(a.y >> 16) + bf2f(b2.y >> 16);
            }
            *(float4*)&Xs[row][kk] = xv;
            *(float4*)&Wt[row][kk] = *(const float4*)&Wsrc[(size_t)(g0 + row) * 256 + kb + kk];
        }
        __syncthreads();
#pragma unroll
        for (int kk = 0; kk < 64; kk += 4) {
            float4 xv[4], wv[4];
#pragma unroll
            for (int i = 0; i < 4; ++i) xv[i] = *(const float4*)&Xs[ty * 4 + i][kk];
#pragma unroll
            for (int j = 0; j < 4; ++j) wv[j] = *(const float4*)&Wt[tx * 4 + j][kk];
#pragma unroll
            for (int i = 0; i < 4; ++i)
#pragma unroll
                for (int j = 0; j < 4; ++j)
                    acc[i][j] += xv[i].x * wv[j].x + xv[i].y * wv[j].y + xv[i].z * wv[j].z + xv[i].w * wv[j].w;
        }
    }
    const int seg = half * 2 + z;
#pragma unroll
    for (int i = 0; i < 4; ++i)
#pragma unroll
        for (int j = 0; j < 4; ++j)
            gates[(size_t)seg * 65536 + (size_t)(ty * 4 + i) * 1024 + g0 + tx * 4 + j] = acc[i][j];

    // MODE 2 runs after conv2: one block reduces pmax -> t2rel
    if (MODE == 2 && blockIdx.x == 0 && half == 0 && z == 0) {
        for (int i = t; i < B_ * 64; i += 256) {
            int b = i >> 6, r = i & 63;
            if (r < R_) {
                float m = -3.0e38f;
#pragma unroll
                for (int ch = 0; ch < 8; ++ch) m = fmaxf(m, pmax[((size_t)b * 8 + ch) * 64 + r]);
                t2rel[b * R_ + r] = m;
            }
        }
    }
}

// ---------------- attention partial (64-l chunks) with fused LSTM finish ----------------
__global__ __launch_bounds__(256) void k_attn_part(
    const float* __restrict__ gates, const float* __restrict__ b_ih, const float* __restrict__ b_hh,
    const float* __restrict__ c_in, float* __restrict__ c_out, float* __restrict__ h_out,
    const unsigned short* __restrict__ encbf,
    float* __restrict__ mixp, float* __restrict__ stats) {
    int b = blockIdx.y, ch = blockIdx.x, t = threadIdx.x;
    __shared__ float hs[E_];
    __shared__ float scp[64][4];
    __shared__ float sc[64];
    {
        size_t ba = (size_t)b * 1024;
        float g4[4];
#pragma unroll
        for (int g = 0; g < 4; ++g) {
            float acc = b_ih[g * 256 + t] + b_hh[g * 256 + t];
#pragma unroll
            for (int seg = 0; seg < 4; ++seg) acc += gates[(size_t)seg * 65536 + ba + g * 256 + t];
            g4[g] = acc;
        }
        float c = sigmoidf_(g4[1]) * c_in[b * H_ + t] + sigmoidf_(g4[0]) * tanhf(g4[2]);
        float hv = sigmoidf_(g4[3]) * tanhf(c);
        hs[t] = hv;
        if (ch == 0) { h_out[b * H_ + t] = hv; c_out[b * H_ + t] = c; }
    }
    __syncthreads();
    {
        int row = t >> 2, es = t & 3;
        const uint4* p = (const uint4*)&encbf[((size_t)b * L_ + ch * 64 + row) * E_ + es * 64];
        float acc = 0.f;
#pragma unroll
        for (int k = 0; k < 8; ++k) {
            uint4 q = p[k];
            int e0 = es * 64 + k * 8;
            acc += bf2f(q.x & 0xffffu) * hs[e0] + bf2f(q.x >> 16) * hs[e0 + 1]
                 + bf2f(q.y & 0xffffu) * hs[e0 + 2] + bf2f(q.y >> 16) * hs[e0 + 3]
                 + bf2f(q.z & 0xffffu) * hs[e0 + 4] + bf2f(q.z >> 16) * hs[e0 + 5]
                 + bf2f(q.w & 0xffffu) * hs[e0 + 6] + bf2f(q.w >> 16) * hs[e0 + 7];
        }
        scp[row][es] = acc;
    }
    __syncthreads();
    if (t < 64) {
        float v = scp[t][0] + scp[t][1] + scp[t][2] + scp[t][3];
        float m = v;
#pragma unroll
        for (int off = 32; off; off >>= 1) m = fmaxf(m, __shfl_xor(m, off));
        float ev = expf(v - m);
        float s = ev;
#pragma unroll
        for (int off = 32; off; off >>= 1) s += __shfl_xor(s, off);
        sc[t] = ev;
        if (t == 0) {
            stats[((size_t)b * 8 + ch) * 2] = m;
            stats[((size_t)b * 8 + ch) * 2 + 1] = s;
        }
    }
    __syncthreads();
    float acc = 0.f;
    const unsigned short* base = &encbf[((size_t)b * L_ + ch * 64) * E_ + t];
#pragma unroll 8
    for (int l = 0; l < 64; ++l) acc += sc[l] * bf2f((unsigned)base[(size_t)l * E_]);
    mixp[((size_t)b * 8 + ch) * E_ + t] = acc;
}

// ---------------- post1: combine + attn-out GEMV (split-K) ----------------
__global__ __launch_bounds__(256) void k_post1(
    const float* __restrict__ mixp, const float* __restrict__ stats,
    const float* __restrict__ h, const float* __restrict__ WT_attn,
    const float* __restrict__ b_attn, float* __restrict__ aout) {
    int b = blockIdx.x, oc = blockIdx.y, t = threadIdx.x;
    __shared__ float cat[512];
    __shared__ float red[16][16][4];
    {
        float M = -3.0e38f;
#pragma unroll
        for (int i = 0; i < 8; ++i) M = fmaxf(M, stats[(b * 8 + i) * 2]);
        float denom = 0.f, mixv = 0.f;
#pragma unroll
        for (int i = 0; i < 8; ++i) {
            float w = expf(stats[(b * 8 + i) * 2] - M);
            denom += stats[(b * 8 + i) * 2 + 1] * w;
            mixv += mixp[((size_t)b * 8 + i) * E_ + t] * w;
        }
        cat[t] = mixv / denom;
        cat[256 + t] = h[b * H_ + t];
    }
    __syncthreads();
    int ocol = t & 15, ks = t >> 4;
    int o4 = oc * 64 + ocol * 4;
    float a0 = 0.f, a1 = 0.f, a2 = 0.f, a3 = 0.f;
    const float* wp = &WT_attn[(size_t)(ks * 32) * 256 + o4];
#pragma unroll 8
    for (int k = 0; k < 32; ++k) {
        float4 w = *(const float4*)&wp[(size_t)k * 256];
        float cv = cat[ks * 32 + k];
        a0 += cv * w.x; a1 += cv * w.y; a2 += cv * w.z; a3 += cv * w.w;
    }
    red[ks][ocol][0] = a0; red[ks][ocol][1] = a1; red[ks][ocol][2] = a2; red[ks][ocol][3] = a3;
    __syncthreads();
    if (t < 64) {
        int oc2 = t >> 2, j = t & 3;
        float s = 0.f;
#pragma unroll
        for (int k2 = 0; k2 < 16; ++k2) s += red[k2][oc2][j];
        int o = oc * 64 + t;
        aout[b * E_ + o] = tanhf(s + b_attn[o]);
    }
}

// ---------------- post2: ocontrib (split-K over c) ----------------
__global__ __launch_bounds__(256) void k_post2(
    const float* __restrict__ aout, const float* __restrict__ wpk,
    float* __restrict__ cr0, float* __restrict__ fullv, float* __restrict__ cr2) {
    int b = blockIdx.x, m = blockIdx.y, t = threadIdx.x;
    __shared__ float os[256];
    __shared__ float red[4][64][4];
    os[t] = aout[b * E_ + t];
    __syncthreads();
    int ocol = t & 63, cs = t >> 6;
    int o4 = ocol * 4;
    const float* wp = &wpk[(size_t)m * 65536 + (size_t)(cs * 64) * 256 + o4];
    float a0 = 0.f, a1 = 0.f, a2 = 0.f, a3 = 0.f;
#pragma unroll 8
    for (int c = 0; c < 64; ++c) {
        float4 w = *(const float4*)&wp[(size_t)c * 256];
        float v = os[cs * 64 + c];
        a0 += v * w.x; a1 += v * w.y; a2 += v * w.z; a3 += v * w.w;
    }
    red[cs][ocol][0] = a0; red[cs][ocol][1] = a1; red[cs][ocol][2] = a2; red[cs][ocol][3] = a3;
    __syncthreads();
    int oc2 = t >> 2, j = t & 3;
    float s = red[0][oc2][j] + red[1][oc2][j] + red[2][oc2][j] + red[3][oc2][j];
    float* dst = (m == 0) ? cr0 : (m == 1) ? fullv : cr2;
    dst[b * E_ + t] = s;
}

// ---------------- conv MFMA: 64l x 256o, 8 waves (2 o-frags each), B prefetch depth 4 ----------------
template <bool FUSE_HEADS, bool WRITE_OUT, bool FUSE_REL>
__global__ __launch_bounds__(512, 4) void k_conv_mfma(
    const unsigned short* __restrict__ encbf, const unsigned short* __restrict__ bp,
    const float* __restrict__ bias, const float* __restrict__ fullv,
    const float* __restrict__ cr0, const float* __restrict__ cr2,
    unsigned short* __restrict__ enc_out,
    const float* __restrict__ w_e1, const float* __restrict__ b_e1,
    const float* __restrict__ w_e2, const float* __restrict__ b_e2,
    float* __restrict__ o1, float* __restrict__ o2,
    const unsigned short* __restrict__ wprel, const float* __restrict__ b_rel,
    const int* __restrict__ T, float* __restrict__ pmax) {
    const int b = blockIdx.y, l0 = blockIdx.x * 64;
    const int t = threadIdx.x, lane = t & 63, wid = t >> 6;
    __shared__ unsigned short As[66 * 256];
    __shared__ float hsum[2][FUSE_HEADS ? 8 : 1][FUSE_HEADS ? 64 : 1];
    __shared__ float pm[FUSE_REL ? 8 : 1][2][16];
    __shared__ int Tm[FUSE_REL ? 64 : 1];

    if (FUSE_REL && t < 64) Tm[t] = T[b * L_ + l0 + t];

    // stage A (bf16 copy, XOR-swizzled, zero halo)
    for (int u = t; u < 66 * 32; u += 512) {
        int row = u >> 5, cu = u & 31;
        int l = l0 - 1 + row;
        uint4 v = {0u, 0u, 0u, 0u};
        if (l >= 0 && l < L_) v = *(const uint4*)&encbf[((size_t)b * L_ + l) * E_ + cu * 8];
        *(uint4*)&As[row * 256 + ((cu ^ (row & 7)) << 3)] = v;
    }
    __syncthreads();

    const int wo2 = wid * 2;                 // this wave's 2 o-frags (32 o)
    f32x4 zero = {0.f, 0.f, 0.f, 0.f};
    f32x4 acc[4][2];
#pragma unroll
    for (int i = 0; i < 4; ++i) { acc[i][0] = zero; acc[i][1] = zero; }
    const int arow = lane & 15, agrp = lane >> 4;
    const unsigned short* bp0 = &bp[((size_t)wo2 * 24 * 64 + lane) * 8];
    const unsigned short* bp1 = &bp[((size_t)(wo2 + 1) * 24 * 64 + lane) * 8];

    // B circular prefetch, depth 4 (static indices via full unroll)
    bf16x8 bq[4][2];
#pragma unroll
    for (int d = 0; d < 4; ++d) {
        bq[d][0] = *(const bf16x8*)&bp0[(size_t)d * 512];
        bq[d][1] = *(const bf16x8*)&bp1[(size_t)d * 512];
    }
#pragma unroll
    for (int kc = 0; kc < 24; ++kc) {
        const int slot = kc & 3;
        bf16x8 b0 = bq[slot][0], b1 = bq[slot][1];
        if (kc + 4 < 24) {
            bq[slot][0] = *(const bf16x8*)&bp0[(size_t)(kc + 4) * 512];
            bq[slot][1] = *(const bf16x8*)&bp1[(size_t)(kc + 4) * 512];
        }
        const int k = kc >> 3;
        const int g = ((kc & 7) << 2) + agrp;
#pragma unroll
        for (int mi = 0; mi < 4; ++mi) {
            int r = mi * 16 + arow + k;
            bf16x8 a = *(const bf16x8*)&As[r * 256 + ((g ^ (r & 7)) << 3)];
            acc[mi][0] = __builtin_amdgcn_mfma_f32_16x16x32_bf16(a, b0, acc[mi][0], 0, 0, 0);
            acc[mi][1] = __builtin_amdgcn_mfma_f32_16x16x32_bf16(a, b1, acc[mi][1], 0, 0, 0);
        }
    }

    float biasv[2], c0v[2], c2v[2], we1v[2], we2v[2];
#pragma unroll
    for (int ni = 0; ni < 2; ++ni) {
        int o = (wo2 + ni) * 16 + (lane & 15);
        biasv[ni] = bias[o] + fullv[b * E_ + o];
        c0v[ni] = cr0[b * E_ + o];
        c2v[ni] = cr2[b * E_ + o];
        if (FUSE_HEADS) { we1v[ni] = w_e1[o]; we2v[ni] = w_e2[o]; }
    }
    __syncthreads();   // done reading As; reuse as output tile

#pragma unroll
    for (int mi = 0; mi < 4; ++mi) {
#pragma unroll
        for (int r = 0; r < 4; ++r) {
            int lloc = mi * 16 + agrp * 4 + r;
            int lrow = l0 + lloc;
            float p1 = 0.f, p2 = 0.f;
#pragma unroll
            for (int ni = 0; ni < 2; ++ni) {
                int o = (wo2 + ni) * 16 + (lane & 15);
                float vv = acc[mi][ni][r] + biasv[ni];
                if (lrow == 0) vv -= c0v[ni];
                if (lrow == L_ - 1) vv -= c2v[ni];
                if (WRITE_OUT || FUSE_REL) {
                    int idx = FUSE_REL ? (lloc * 256 + ((((o >> 3) ^ (lloc & 7))) << 3) + (o & 7))
                                       : (lloc * 256 + o);
                    As[idx] = f2bf(vv);
                }
                if (FUSE_HEADS) {
                    float gv = geluf_(vv);
                    p1 += gv * we1v[ni];
                    p2 += gv * we2v[ni];
                }
            }
            if (FUSE_HEADS) {
#pragma unroll
                for (int off = 1; off < 16; off <<= 1) {
                    p1 += __shfl_xor(p1, off);
                    p2 += __shfl_xor(p2, off);
                }
                if ((lane & 15) == 0) {
                    hsum[0][wid][lloc] = p1;
                    hsum[1][wid][lloc] = p2;
                }
            }
        }
    }
    __syncthreads();

    if (WRITE_OUT) {
        for (int u = t; u < 64 * 32; u += 512) {
            int row = u >> 5, cu = u & 31;
            int src = FUSE_REL ? (row * 256 + ((cu ^ (row & 7)) << 3)) : (row * 256 + cu * 8);
            uint4 q = *(const uint4*)&As[src];
            *(uint4*)&enc_out[((size_t)b * L_ + l0 + row) * E_ + cu * 8] = q;
            if (FUSE_REL) {
                unsigned qa[4] = {q.x, q.y, q.z, q.w};
#pragma unroll
                for (int j = 0; j < 4; ++j) {
                    unsigned lo = f2bf(geluf_(bf2f(qa[j] & 0xffffu)));
                    unsigned hi = f2bf(geluf_(bf2f(qa[j] >> 16)));
                    qa[j] = lo | (hi << 16);
                }
                uint4 gq = {qa[0], qa[1], qa[2], qa[3]};
                *(uint4*)&As[src] = gq;
            }
        }
    }
    if (FUSE_HEADS && t < 128) {
        int hh = t >> 6, row = t & 63;
        float s = 0.f;
#pragma unroll
        for (int w = 0; w < 8; ++w) s += hsum[hh][w][row];
        float* dst = hh ? o2 : o1;
        const float* bb = hh ? b_e2 : b_e1;
        dst[(size_t)b * L_ + l0 + row] = s + bb[0];
    }
    if (FUSE_REL) {
        __syncthreads();
        const int mi = wid & 3, njp = wid >> 2;
        f32x4 accr[2] = {zero, zero};
        const int ar = mi * 16 + arow;
#pragma unroll 2
        for (int kc = 0; kc < 8; ++kc) {
            int g = (kc << 2) + agrp;
            bf16x8 av = *(const bf16x8*)&As[ar * 256 + ((g ^ (ar & 7)) << 3)];
#pragma unroll
            for (int q = 0; q < 2; ++q) {
                int nj = njp * 2 + q;
                bf16x8 bv = *(const bf16x8*)&wprel[(((size_t)nj * 8 + kc) * 64 + lane) * 8];
                accr[q] = __builtin_amdgcn_mfma_f32_16x16x32_bf16(av, bv, accr[q], 0, 0, 0);
            }
        }
#pragma unroll
        for (int q = 0; q < 2; ++q) {
            int nj = njp * 2 + q;
            int rr = nj * 16 + (lane & 15);
            float brel = (rr < R_) ? b_rel[rr] : 0.f;
            float v = -3.0e38f;
#pragma unroll
            for (int rg = 0; rg < 4; ++rg) {
                int lloc = mi * 16 + agrp * 4 + rg;
                float pen = (Tm[lloc] > 0) ? 0.f : NEG_;
                v = fmaxf(v, accr[q][rg] + brel - pen);
            }
            v = fmaxf(v, __shfl_xor(v, 16));
            v = fmaxf(v, __shfl_xor(v, 32));
            if (lane < 16) pm[wid][q][lane] = v;
        }
        __syncthreads();
        if (t < 64) {
            int nj = t >> 4, rl = t & 15;
            int q = nj & 1, wb = (nj >> 1) * 4;
            float m = fmaxf(fmaxf(pm[wb][q][rl], pm[wb + 1][q][rl]),
                            fmaxf(pm[wb + 2][q][rl], pm[wb + 3][q][rl]));
            pmax[((size_t)b * 8 + blockIdx.x) * 64 + t] = m;
        }
    }
}

// ---------------- driver ----------------
extern "C" void kernel_launch(void* const* d_in, const int* in_sizes, int n_in,
                              void* d_out, int out_size, void* d_ws, size_t ws_size,
                              hipStream_t stream) {
    const float* encoder_o = (const float*)d_in[0];
    const float* h0 = (const float*)d_in[1];
    const float* c0 = (const float*)d_in[2];
    const float* sos_emb = (const float*)d_in[3];
    const float* rel_emb = (const float*)d_in[4];
    const float* W_ih = (const float*)d_in[5];
    const float* W_hh = (const float*)d_in[6];
    const float* b_ih = (const float*)d_in[7];
    const float* b_hh = (const float*)d_in[8];
    const float* W_attn = (const float*)d_in[9];
    const float* b_attn = (const float*)d_in[10];
    const float* conv_rel_w = (const float*)d_in[11];
    const float* conv_rel_b = (const float*)d_in[12];
    const float* conv_ent_w = (const float*)d_in[13];
    const float* conv_ent_b = (const float*)d_in[14];
    const float* W_rel = (const float*)d_in[15];
    const float* b_rel = (const float*)d_in[16];
    const float* w_e1 = (const float*)d_in[17];
    const float* b_e1 = (const float*)d_in[18];
    const float* w_e2 = (const float*)d_in[19];
    const float* b_e2 = (const float*)d_in[20];
    const int* T = (const int*)d_in[21];
    const int* R_in = (const int*)d_in[22];
    const int* S_K1 = (const int*)d_in[23];
    const int* S_K2 = (const int*)d_in[24];

    float* out = (float*)d_out;
    float* t1e1 = out;
    float* t1e2 = out + 32768;
    float* t2rel = out + 65536;
    float* t3e1 = out + 68736;
    float* t3e2 = out + 101504;

    float* ws = (float*)d_ws;
    size_t off = 0;
    unsigned short* encBF0 = (unsigned short*)(ws + off); off += (size_t)B_ * L_ * E_ / 2;
    unsigned short* encA = (unsigned short*)(ws + off); off += (size_t)B_ * L_ * E_ / 2;
    unsigned short* encB = (unsigned short*)(ws + off); off += (size_t)B_ * L_ * E_ / 2;
    float* gates = ws + off; off += 4 * 65536;
    float* hbuf = ws + off; off += B_ * H_;
    float* cb1 = ws + off; off += B_ * H_;
    float* cb2 = ws + off; off += B_ * H_;
    float* cb3 = ws + off; off += B_ * H_;
    float* mixp = ws + off; off += (size_t)B_ * 8 * E_;
    float* stats = ws + off; off += B_ * 8 * 2;
    float* aoutb = ws + off; off += B_ * E_;
    float* fullv = ws + off; off += B_ * E_;
    float* cr0 = ws + off; off += B_ * E_;
    float* cr2 = ws + off; off += B_ * E_;
    float* pmax = ws + off; off += B_ * 8 * 64;
    float* wpkE = ws + off; off += 3 * 65536;
    float* wpkR = ws + off; off += 3 * 65536;
    float* WTat = ws + off; off += 131072;
    unsigned short* bpE = (unsigned short*)(ws + off); off += 16 * 24 * 64 * 8 / 2;
    unsigned short* bpR = (unsigned short*)(ws + off); off += 16 * 24 * 64 * 8 / 2;
    unsigned short* wpR = (unsigned short*)(ws + off); off += 4 * 8 * 64 * 8 / 2;

    dim3 convGrid(8, B_);
    dim3 attnGrid(8, B_);
    dim3 lstmGrid(16, 2, 2);
    dim3 p1Grid(B_, 4);
    dim3 p2Grid(B_, 3);

    // one-time packs (single launch)
    k_packs<<<9416, 256, 0, stream>>>(encoder_o, encBF0, conv_ent_w, conv_rel_w,
                                      bpE, bpR, W_rel, wpR, wpkE, wpkR, W_attn, WTat);

    // ---- step 1 ----
    k_lstm_gemm<0><<<lstmGrid, 256, 0, stream>>>(sos_emb, nullptr, nullptr, nullptr, nullptr,
                                                 h0, W_ih, W_hh, gates, nullptr, nullptr);
    k_attn_part<<<attnGrid, 256, 0, stream>>>(gates, b_ih, b_hh, c0, cb1, hbuf, encBF0, mixp, stats);
    k_post1<<<p1Grid, 256, 0, stream>>>(mixp, stats, hbuf, WTat, b_attn, aoutb);
    k_post2<<<p2Grid, 256, 0, stream>>>(aoutb, wpkE, cr0, fullv, cr2);
    k_conv_mfma<true, true, false><<<convGrid, 512, 0, stream>>>(
        encBF0, bpE, conv_ent_b, fullv, cr0, cr2, encA,
        w_e1, b_e1, w_e2, b_e2, t1e1, t1e2, nullptr, nullptr, nullptr, nullptr);

    // ---- step 2 ----
    k_lstm_gemm<1><<<lstmGrid, 256, 0, stream>>>(nullptr, encA, S_K1, S_K2, nullptr,
                                                 hbuf, W_ih, W_hh, gates, nullptr, nullptr);
    k_attn_part<<<attnGrid, 256, 0, stream>>>(gates, b_ih, b_hh, cb1, cb2, hbuf, encA, mixp, stats);
    k_post1<<<p1Grid, 256, 0, stream>>>(mixp, stats, hbuf, WTat, b_attn, aoutb);
    k_post2<<<p2Grid, 256, 0, stream>>>(aoutb, wpkR, cr0, fullv, cr2);
    k_conv_mfma<false, true, true><<<convGrid, 512, 0, stream>>>(
        encA, bpR, conv_rel_b, fullv, cr0, cr2, encB,
        nullptr, nullptr, nullptr, nullptr, nullptr, nullptr, wpR, b_rel, T, pmax);

    // ---- step 3 (lstm3 also reduces pmax -> t2rel) ----
    k_lstm_gemm<2><<<lstmGrid, 256, 0, stream>>>(rel_emb, nullptr, nullptr, nullptr, R_in,
                                                 hbuf, W_ih, W_hh, gates, pmax, t2rel);
    k_attn_part<<<attnGrid, 256, 0, stream>>>(gates, b_ih, b_hh, cb2, cb3, hbuf, encB, mixp, stats);
    k_post1<<<p1Grid, 256, 0, stream>>>(mixp, stats, hbuf, WTat, b_attn, aoutb);
    k_post2<<<p2Grid, 256, 0, stream>>>(aoutb, wpkE, cr0, fullv, cr2);
    k_conv_mfma<true, false, false><<<convGrid, 512, 0, stream>>>(
        encB, bpE, conv_ent_b, fullv, cr0, cr2, nullptr,
        w_e1, b_e1, w_e2, b_e2, t3e1, t3e2, nullptr, nullptr, nullptr, nullptr);
}